// Round 14
// baseline (290.351 us; speedup 1.0000x reference)
//
#include <hip/hip_runtime.h>
#include <cmath>

#define CC 21
#define HH 512
#define WW 512
#define HWSZ (HH*WW)
#define CHW (CC*HWSZ)
#define NITERS 5
#define ROWF (CC*WW)          // 10752 elems per image row in HWC

struct K9 { float k[9]; };

__device__ __forceinline__ float bf16_to_f(unsigned short v) {
    union { unsigned int i; float f; } cv; cv.i = ((unsigned int)v) << 16; return cv.f;
}
__device__ __forceinline__ unsigned short f_to_bf16(float f) {
    union { float f; unsigned int i; } cv; cv.f = f;
    unsigned int b = cv.i + 0x7FFFu + ((cv.i >> 16) & 1u);   // RNE
    return (unsigned short)(b >> 16);
}
__device__ __forceinline__ float lo_bf(unsigned int u) {
    union { unsigned int i; float f; } cv; cv.i = u << 16; return cv.f;
}
__device__ __forceinline__ float hi_bf(unsigned int u) {
    union { unsigned int i; float f; } cv; cv.i = u & 0xFFFF0000u; return cv.f;
}
__device__ __forceinline__ unsigned int pack2_bf(float a, float b) {
    return (unsigned int)f_to_bf16(a) | ((unsigned int)f_to_bf16(b) << 16);
}

// one-time: unaries (HWC fp32) -> bf16
__global__ void convert_u16_kernel(const float* __restrict__ u, unsigned short* __restrict__ u16) {
    size_t i = ((size_t)blockIdx.x*256 + threadIdx.x) * 4;
    float4 f = *(const float4*)(u + i);
    ushort4 o;
    o.x = f_to_bf16(f.x); o.y = f_to_bf16(f.y);
    o.z = f_to_bf16(f.z); o.w = f_to_bf16(f.w);
    *(ushort4*)(u16 + i) = o;
}

// spT[h*W + w] = sp_map[w*W + h]
__global__ void transpose_sp_kernel(const int* __restrict__ sp, int* __restrict__ spT) {
    int p = blockIdx.x*256 + threadIdx.x;
    int h = p >> 9, w = p & (WW - 1);
    spT[p] = sp[w*WW + h];
}

// M = CM @ (SKW + BKW)
__global__ void precomp_M_kernel(const float* __restrict__ skw, const float* __restrict__ bkw,
                                 const float* __restrict__ cm, float* __restrict__ M) {
    int i = blockIdx.x * blockDim.x + threadIdx.x;
    if (i >= CC*CC) return;
    int r = i / CC, k = i - r*CC;
    float a = 0.f;
    for (int j = 0; j < CC; ++j) a += cm[r*CC + j] * (skw[j*CC + k] + bkw[j*CC + k]);
    M[i] = a;
}

// iter-0: sm0 = softmax(u) -> sm16 (vectorized via LDS) + smf/redacc slot-0.
__launch_bounds__(256)
__global__ void init_sm_kernel(const float* __restrict__ unaries,
                               unsigned short* __restrict__ sm16,
                               float* __restrict__ smf,
                               const int* __restrict__ spT,
                               const int* __restrict__ sp_indices,
                               float* __restrict__ redacc) {
    __shared__ __align__(16) float lu[CC*256];
    __shared__ float acc[44];
    __shared__ int anyC;
    unsigned short* smS = (unsigned short*)lu;   // alias, used after lu dead
    int bid = blockIdx.x;
    int h = bid >> 1, w0 = (bid & 1) << 8;
    int tx = threadIdx.x;
    if (tx < 44) acc[tx] = 0.f;
    if (tx == 0) anyC = 0;
    {
        const float4* src = (const float4*)(unaries + (size_t)h*ROWF + w0*CC);
        float4* dst = (float4*)lu;
        #pragma unroll
        for (int j = 0; j < 6; ++j) {
            int idx = j*256 + tx;
            if (idx < CC*256/4) dst[idx] = src[idx];
        }
    }
    __syncthreads();
    int p = h*WW + w0 + tx;
    float v[CC]; float m = -1e30f;
    #pragma unroll
    for (int c = 0; c < CC; ++c) { v[c] = lu[tx*CC + c]; m = fmaxf(m, v[c]); }
    float s = 0.f;
    #pragma unroll
    for (int c = 0; c < CC; ++c) { v[c] = expf(v[c] - m); s += v[c]; }
    float inv = 1.f / s;
    #pragma unroll
    for (int c = 0; c < CC; ++c) v[c] *= inv;

    int idx = sp_indices[0];
    int lab = spT[p];
    if (lab == idx || lab == idx + 1) {
        int mk = (lab == idx) ? 0 : 1;
        anyC = 1;
        atomicAdd(&acc[42 + mk], 1.f);
        for (int c = 0; c < CC; ++c) {
            smf[(size_t)c*HWSZ + p] = v[c];
            atomicAdd(&acc[mk*21 + c], expf(v[c]));
        }
    }
    __syncthreads();                 // all lu reads done -> smS writable
    #pragma unroll
    for (int c = 0; c < CC; ++c) smS[c*256 + tx] = f_to_bf16(v[c]);
    if (anyC && tx < 44) atomicAdd(&redacc[tx], acc[tx]);
    __syncthreads();
    {   // vectorized sm16 stores: 672 uint4, c = task>>5, q = task&31
        unsigned short* dstb = sm16 + (size_t)h*WW + w0;
        #pragma unroll
        for (int j = 0; j < 3; ++j) {
            int task = j*256 + tx;
            if (task < 672) {
                int c = task >> 5, q = task & 31;
                *(uint4*)(dstb + (size_t)c*HWSZ + q*8) = *(const uint4*)(smS + c*256 + q*8);
            }
        }
    }
}

// FULL separable 9x9 blur (zero pad): sm16 -> mp16. 8 px/thread, high TLP.
__launch_bounds__(256)
__global__ void blur_kernel(const unsigned short* __restrict__ sm16,
                            unsigned short* __restrict__ mp16, K9 kk) {
    size_t idx = ((size_t)blockIdx.x*256 + threadIdx.x) * 8;   // (c,h,w0)
    int p  = (int)(idx & (HWSZ - 1));
    int h  = p >> 9;
    int w0 = p & (WW - 1);
    const unsigned short* rowbase = sm16 + (idx - w0);

    float win[24];
    #pragma unroll
    for (int j = 0; j < 24; ++j) win[j] = 0.f;

    bool hasL = (w0 >= 8), hasR = (w0 <= WW - 16);
    #pragma unroll
    for (int t = 0; t < 9; ++t) {
        int hh = h + t - 4;
        if (hh >= 0 && hh < HH) {
            const unsigned short* r = rowbase + (t - 4)*WW + w0;
            float kt = kk.k[t];
            if (hasL) {
                uint4 v = *(const uint4*)(r - 8);
                win[0] += kt*lo_bf(v.x); win[1] += kt*hi_bf(v.x);
                win[2] += kt*lo_bf(v.y); win[3] += kt*hi_bf(v.y);
                win[4] += kt*lo_bf(v.z); win[5] += kt*hi_bf(v.z);
                win[6] += kt*lo_bf(v.w); win[7] += kt*hi_bf(v.w);
            }
            {
                uint4 v = *(const uint4*)(r);
                win[8]  += kt*lo_bf(v.x); win[9]  += kt*hi_bf(v.x);
                win[10] += kt*lo_bf(v.y); win[11] += kt*hi_bf(v.y);
                win[12] += kt*lo_bf(v.z); win[13] += kt*hi_bf(v.z);
                win[14] += kt*lo_bf(v.w); win[15] += kt*hi_bf(v.w);
            }
            if (hasR) {
                uint4 v = *(const uint4*)(r + 8);
                win[16] += kt*lo_bf(v.x); win[17] += kt*hi_bf(v.x);
                win[18] += kt*lo_bf(v.y); win[19] += kt*hi_bf(v.y);
                win[20] += kt*lo_bf(v.z); win[21] += kt*hi_bf(v.z);
                win[22] += kt*lo_bf(v.w); win[23] += kt*hi_bf(v.w);
            }
        }
    }
    float o[8];
    #pragma unroll
    for (int j = 0; j < 8; ++j) {
        float a = 0.f;
        #pragma unroll
        for (int t = 0; t < 9; ++t) a += kk.k[t] * win[j + t + 4];
        o[j] = a;
    }
    uint4 ov;
    ov.x = pack2_bf(o[0],o[1]); ov.y = pack2_bf(o[2],o[3]);
    ov.z = pack2_bf(o[4],o[5]); ov.w = pack2_bf(o[6],o[7]);
    *(uint4*)(mp16 + idx) = ov;
}

// final: ALL c-strided global streams via LDS uint4 (G13).
// mp16 ->(uint4) mpS -> b[] regs; M-mix -> qlds (fp32, unioned with mpS);
// softmax -> smS (same union) ->(uint4) sm16. Clique fixup + smf/redacc sparse.
__launch_bounds__(256)
__global__ void final_kernel(const unsigned short* __restrict__ mp16,
                             unsigned short* __restrict__ sm16,
                             float* __restrict__ smf,
                             float* __restrict__ outHWC,
                             const unsigned short* __restrict__ u16,
                             const int* __restrict__ spT,
                             const int* __restrict__ sp_indices, int iter,
                             const float* __restrict__ Mg,
                             const float* __restrict__ lwg, const float* __restrict__ hwg,
                             K9 kk, float* __restrict__ redacc, int last) {
    __shared__ __align__(16) float qlds[CC*256];          // 21504 B; aliases mpS/smS
    __shared__ __align__(16) unsigned short lu16[CC*256]; // 10752 B
    __shared__ float Bsh[42];
    __shared__ float acc[44];
    __shared__ int anyC;
    unsigned short* mpS = (unsigned short*)qlds;          // [CC*256] bf16 alias

    int bid = blockIdx.x;                      // 0..1023
    int xcd = bid & 7, tt = bid >> 3;
    int h  = xcd*64 + (tt >> 1);
    int w0 = (tt & 1) << 8;
    int tx = threadIdx.x;

    if (tx < 44) acc[tx] = 0.f;
    if (tx == 0) anyC = 0;
    {   // inline B from accumulated partials of this iteration's clique
        const float* rc = redacc + iter*64;
        if (tx < 42) {
            float s = rc[tx], n = rc[42 + tx/21];
            Bsh[tx] = logf((float)HWSZ - n + s);
        }
    }
    // stage u16 half-row (uint4, 672)
    {
        const uint4* src = (const uint4*)(u16 + (size_t)h*ROWF + w0*CC);
        uint4* dst = (uint4*)lu16;
        #pragma unroll
        for (int j = 0; j < 3; ++j) {
            int idx = j*256 + tx;
            if (idx < 672) dst[idx] = src[idx];
        }
    }
    // stage mp16 c-strips (uint4, 672): c = task>>5, q = task&31
    {
        const unsigned short* base = mp16 + (size_t)h*WW + w0;
        #pragma unroll
        for (int j = 0; j < 3; ++j) {
            int task = j*256 + tx;
            if (task < 672) {
                int c = task >> 5, q = task & 31;
                *(uint4*)(mpS + c*256 + q*8) = *(const uint4*)(base + (size_t)c*HWSZ + q*8);
            }
        }
    }
    __syncthreads();

    int w = w0 + tx;
    int p = h*WW + w;

    // blurred field from LDS -> the ONLY register array
    float b[CC];
    #pragma unroll
    for (int c = 0; c < CC; ++c) b[c] = bf16_to_f(mpS[c*256 + tx]);
    __syncthreads();                 // mpS dead -> qlds region writable

    // separable norm = s(h)*s(w)
    float sv = 0.f, swn = 0.f;
    #pragma unroll
    for (int t = 0; t < 9; ++t) {
        int hh = h + t - 4; if (hh >= 0 && hh < HH) sv  += kk.k[t];
        int wi = w + t - 4; if (wi >= 0 && wi < WW) swn += kk.k[t];
    }
    float invnorm = 1.f / (sv * swn);

    int idxv = sp_indices[iter];
    int lab  = spT[p];
    bool in1 = (lab == idxv), in2 = (lab == idxv + 1);
    bool incur = in1 | in2;
    float hw0 = hwg[0], hw1 = hwg[1];
    float attc = hw0 + hw1;

    // M-mix (branch-free); qv -> qlds (own slots only)
    float qmax = -1e30f;
    #pragma unroll
    for (int c = 0; c < CC; ++c) {
        float pw = 0.f;
        #pragma unroll
        for (int k = 0; k < CC; ++k) pw += Mg[c*CC + k] * b[k];
        float qv = bf16_to_f(lu16[tx*CC + c]) - pw*invnorm - attc;
        qlds[c*256 + tx] = qv;
        qmax = fmaxf(qmax, qv);
    }
    // rare clique fixup (~650 px total; own slots)
    if (incur) {
        qmax = -1e30f;
        for (int c = 0; c < CC; ++c) {
            float smv = smf[(size_t)c*HWSZ + p];
            float qm  = (smv == 0.f) ? 1.f : smv;
            float ft1 = in1 ? Bsh[c]      / qm : 0.f;
            float ft2 = in2 ? Bsh[CC + c] / qm : 0.f;
            float fta = ft1 + ft2;
            float att = lwg[c]*ft1 + hw0*(1.f - ft1) + lwg[CC + c]*fta + hw1*(1.f - fta);
            float qv = qlds[c*256 + tx] + attc - att;
            qlds[c*256 + tx] = qv;
            qmax = fmaxf(qmax, qv);
        }
    }

    if (!last) {
        // softmax: exp from own qlds slots into b[]
        float ssum = 0.f;
        #pragma unroll
        for (int c = 0; c < CC; ++c) {
            float e = expf(qlds[c*256 + tx] - qmax);
            b[c] = e; ssum += e;
        }
        float inv = 1.f / ssum;

        int idx2 = sp_indices[iter + 1];
        bool n1 = (lab == idx2), n2 = (lab == idx2 + 1);
        if (n1 | n2) {
            int mk = n1 ? 0 : 1;
            anyC = 1;
            atomicAdd(&acc[42 + mk], 1.f);
            for (int c = 0; c < CC; ++c) {
                float smv = b[c] * inv;
                smf[(size_t)c*HWSZ + p] = smv;
                atomicAdd(&acc[mk*21 + c], expf(smv));
            }
        }
        __syncthreads();             // all qv reads done -> smS writable
        #pragma unroll
        for (int c = 0; c < CC; ++c) mpS[c*256 + tx] = f_to_bf16(b[c] * inv);
        if (anyC && tx < 44) atomicAdd(&redacc[(iter+1)*64 + tx], acc[tx]);
        __syncthreads();             // smS complete
        {   // vectorized sm16 stores (uint4, 672)
            unsigned short* dstb = sm16 + (size_t)h*WW + w0;
            #pragma unroll
            for (int j = 0; j < 3; ++j) {
                int task = j*256 + tx;
                if (task < 672) {
                    int c = task >> 5, q = task & 31;
                    *(uint4*)(dstb + (size_t)c*HWSZ + q*8) = *(const uint4*)(mpS + c*256 + q*8);
                }
            }
        }
    } else {
        // q5 -> out HWC: gather float4s directly from qlds, transposed index.
        __syncthreads();
        float4* dst = (float4*)(outHWC + (size_t)h*ROWF + w0*CC);
        #pragma unroll
        for (int j = 0; j < 6; ++j) {
            int idx = j*256 + tx;
            if (idx < CC*256/4) {
                int e = idx * 4;              // e = pix*CC + c
                float4 o;
                o.x = qlds[(e       % CC)*256 + (e       / CC)];
                o.y = qlds[((e + 1) % CC)*256 + ((e + 1) / CC)];
                o.z = qlds[((e + 2) % CC)*256 + ((e + 2) / CC)];
                o.w = qlds[((e + 3) % CC)*256 + ((e + 3) / CC)];
                dst[idx] = o;
            }
        }
    }
}

extern "C" void kernel_launch(void* const* d_in, const int* in_sizes, int n_in,
                              void* d_out, int out_size, void* d_ws, size_t ws_size,
                              hipStream_t stream) {
    const float* unaries    = (const float*)d_in[0];
    // d_in[1] = rgb (unused by the reference)
    const int*   sp_map     = (const int*)d_in[2];
    const int*   sp_indices = (const int*)d_in[3];
    const float* skw        = (const float*)d_in[4];
    const float* bkw        = (const float*)d_in[5];
    const float* cm         = (const float*)d_in[6];
    const float* lw         = (const float*)d_in[7];
    const float* hwt        = (const float*)d_in[8];
    float* out = (float*)d_out;

    char* wsb = (char*)d_ws;
    unsigned short* sm16 = (unsigned short*)wsb;                 // CHW bf16
    unsigned short* mp16 = sm16 + CHW;                           // CHW bf16 (blurred)
    unsigned short* u16  = mp16 + CHW;                           // CHW bf16
    float* smf  = (float*)(u16 + CHW);                           // CHW fp32 (sparse use)
    float* M    = smf + CHW;                                     // 441
    float* redacc = M + CC*CC;                                   // 6 slots x 64
    int*   spT  = (int*)(redacc + 6*64);                         // HWSZ ints

    // 9-tap normalized Gaussian, sigma=3 (fp32, matches reference)
    K9 kk;
    {
        float s = 0.f;
        for (int t = 0; t < 9; ++t) {
            float x = (float)(t - 4) / 3.0f;
            kk.k[t] = expf(-0.5f * x * x);
            s += kk.k[t];
        }
        for (int t = 0; t < 9; ++t) kk.k[t] /= s;
    }

    hipMemsetAsync(redacc, 0, 6*64*sizeof(float), stream);
    convert_u16_kernel<<<CHW/1024, 256, 0, stream>>>(unaries, u16);
    transpose_sp_kernel<<<HWSZ/256, 256, 0, stream>>>(sp_map, spT);
    precomp_M_kernel<<<2, 256, 0, stream>>>(skw, bkw, cm, M);
    init_sm_kernel<<<1024, 256, 0, stream>>>(unaries, sm16, smf, spT, sp_indices, redacc);

    for (int it = 0; it < NITERS; ++it) {
        blur_kernel<<<CHW/2048, 256, 0, stream>>>(sm16, mp16, kk);   // full 9x9 blur
        int last = (it == NITERS - 1);
        final_kernel<<<1024, 256, 0, stream>>>(mp16, sm16, smf, out, u16, spT,
                                               sp_indices, it, M, lw, hwt,
                                               kk, redacc, last);
    }
}

// Round 15
// 272.773 us; speedup vs baseline: 1.0644x; 1.0644x over previous
//
#include <hip/hip_runtime.h>
#include <cmath>

#define CC 21
#define HH 512
#define WW 512
#define HWSZ (HH*WW)
#define CHW (CC*HWSZ)
#define NITERS 5
#define ROWF (CC*WW)          // 10752 elems per image row in HWC
#define BR 4                  // blur rows per block

struct K9 { float k[9]; };

__device__ __forceinline__ float bf16_to_f(unsigned short v) {
    union { unsigned int i; float f; } cv; cv.i = ((unsigned int)v) << 16; return cv.f;
}
__device__ __forceinline__ unsigned short f_to_bf16(float f) {
    union { float f; unsigned int i; } cv; cv.f = f;
    unsigned int b = cv.i + 0x7FFFu + ((cv.i >> 16) & 1u);   // RNE
    return (unsigned short)(b >> 16);
}
__device__ __forceinline__ float lo_bf(unsigned int u) {
    union { unsigned int i; float f; } cv; cv.i = u << 16; return cv.f;
}
__device__ __forceinline__ float hi_bf(unsigned int u) {
    union { unsigned int i; float f; } cv; cv.i = u & 0xFFFF0000u; return cv.f;
}
__device__ __forceinline__ unsigned int pack2_bf(float a, float b) {
    return (unsigned int)f_to_bf16(a) | ((unsigned int)f_to_bf16(b) << 16);
}

// one-time: unaries (HWC fp32) -> bf16
__global__ void convert_u16_kernel(const float* __restrict__ u, unsigned short* __restrict__ u16) {
    size_t i = ((size_t)blockIdx.x*256 + threadIdx.x) * 4;
    float4 f = *(const float4*)(u + i);
    ushort4 o;
    o.x = f_to_bf16(f.x); o.y = f_to_bf16(f.y);
    o.z = f_to_bf16(f.z); o.w = f_to_bf16(f.w);
    *(ushort4*)(u16 + i) = o;
}

// spT[h*W + w] = sp_map[w*W + h]
__global__ void transpose_sp_kernel(const int* __restrict__ sp, int* __restrict__ spT) {
    int p = blockIdx.x*256 + threadIdx.x;
    int h = p >> 9, w = p & (WW - 1);
    spT[p] = sp[w*WW + h];
}

// M = CM @ (SKW + BKW)
__global__ void precomp_M_kernel(const float* __restrict__ skw, const float* __restrict__ bkw,
                                 const float* __restrict__ cm, float* __restrict__ M) {
    int i = blockIdx.x * blockDim.x + threadIdx.x;
    if (i >= CC*CC) return;
    int r = i / CC, k = i - r*CC;
    float a = 0.f;
    for (int j = 0; j < CC; ++j) a += cm[r*CC + j] * (skw[j*CC + k] + bkw[j*CC + k]);
    M[i] = a;
}

// iter-0: sm0 = softmax(u) -> sm16 (vectorized via LDS) + smf/redacc slot-0.
__launch_bounds__(256)
__global__ void init_sm_kernel(const float* __restrict__ unaries,
                               unsigned short* __restrict__ sm16,
                               float* __restrict__ smf,
                               const int* __restrict__ spT,
                               const int* __restrict__ sp_indices,
                               float* __restrict__ redacc) {
    __shared__ __align__(16) float lu[CC*256];
    __shared__ float acc[44];
    __shared__ int anyC;
    unsigned short* smS = (unsigned short*)lu;   // alias, used after lu dead
    int bid = blockIdx.x;
    int h = bid >> 1, w0 = (bid & 1) << 8;
    int tx = threadIdx.x;
    if (tx < 44) acc[tx] = 0.f;
    if (tx == 0) anyC = 0;
    {
        const float4* src = (const float4*)(unaries + (size_t)h*ROWF + w0*CC);
        float4* dst = (float4*)lu;
        #pragma unroll
        for (int j = 0; j < 6; ++j) {
            int idx = j*256 + tx;
            if (idx < CC*256/4) dst[idx] = src[idx];
        }
    }
    __syncthreads();
    int p = h*WW + w0 + tx;
    float v[CC]; float m = -1e30f;
    #pragma unroll
    for (int c = 0; c < CC; ++c) { v[c] = lu[tx*CC + c]; m = fmaxf(m, v[c]); }
    float s = 0.f;
    #pragma unroll
    for (int c = 0; c < CC; ++c) { v[c] = __expf(v[c] - m); s += v[c]; }
    float inv = 1.f / s;
    #pragma unroll
    for (int c = 0; c < CC; ++c) v[c] *= inv;

    int idx = sp_indices[0];
    int lab = spT[p];
    if (lab == idx || lab == idx + 1) {
        int mk = (lab == idx) ? 0 : 1;
        anyC = 1;
        atomicAdd(&acc[42 + mk], 1.f);
        for (int c = 0; c < CC; ++c) {
            smf[(size_t)c*HWSZ + p] = v[c];
            atomicAdd(&acc[mk*21 + c], __expf(v[c]));
        }
    }
    __syncthreads();                 // all lu reads done -> smS writable
    #pragma unroll
    for (int c = 0; c < CC; ++c) smS[c*256 + tx] = f_to_bf16(v[c]);
    if (anyC && tx < 44) atomicAdd(&redacc[tx], acc[tx]);
    __syncthreads();
    {   // vectorized sm16 stores: 672 uint4, c = task>>5, q = task&31
        unsigned short* dstb = sm16 + (size_t)h*WW + w0;
        #pragma unroll
        for (int j = 0; j < 3; ++j) {
            int task = j*256 + tx;
            if (task < 672) {
                int c = task >> 5, q = task & 31;
                *(uint4*)(dstb + (size_t)c*HWSZ + q*8) = *(const uint4*)(smS + c*256 + q*8);
            }
        }
    }
}

// LDS-tiled separable 9x9 blur (zero pad): sm16 -> mp16.
// One block per (c, 4-row strip): stage 12 rows once, vertical -> fp32 vres,
// horizontal from fp32 LDS (no reconvert). 2688 blocks, 7 blocks/CU.
__launch_bounds__(256)
__global__ void blur_kernel(const unsigned short* __restrict__ sm16,
                            unsigned short* __restrict__ mp16, K9 kk) {
    __shared__ __align__(16) unsigned short tin[(BR+8)*WW];  // 12288 B
    __shared__ float vres[BR*WW];                            // 8192 B
    int bid = blockIdx.x;
    int c  = bid / (HH/BR);          // 0..20
    int rb = bid - c*(HH/BR);        // 0..127
    int h0 = rb*BR;
    int tx = threadIdx.x;
    const unsigned short* plane = sm16 + (size_t)c*HWSZ;

    // stage rows h0-4 .. h0+7 (768 uint4, 3/thread; wave = one row)
    #pragma unroll
    for (int j = 0; j < 3; ++j) {
        int q = j*256 + tx;          // 0..767
        int r = q >> 6, qw = q & 63;
        int hh = h0 - 4 + r;
        uint4 v = make_uint4(0u,0u,0u,0u);
        if (hh >= 0 && hh < HH) v = *(const uint4*)(plane + hh*WW + qw*8);
        *(uint4*)(tin + r*WW + qw*8) = v;
    }
    __syncthreads();

    int r   = tx >> 6;               // 0..3 (own output row)
    int px0 = (tx & 63) * 8;

    // vertical: 9 taps x 8 px from bf16 tile
    float a0=0,a1=0,a2=0,a3=0,a4=0,a5=0,a6=0,a7=0;
    #pragma unroll
    for (int t = 0; t < 9; ++t) {
        uint4 v = *(const uint4*)(tin + (r + t)*WW + px0);
        float kt = kk.k[t];
        a0 += kt*lo_bf(v.x); a1 += kt*hi_bf(v.x);
        a2 += kt*lo_bf(v.y); a3 += kt*hi_bf(v.y);
        a4 += kt*lo_bf(v.z); a5 += kt*hi_bf(v.z);
        a6 += kt*lo_bf(v.w); a7 += kt*hi_bf(v.w);
    }
    float* vr = vres + r*WW + px0;
    vr[0]=a0; vr[1]=a1; vr[2]=a2; vr[3]=a3; vr[4]=a4; vr[5]=a5; vr[6]=a6; vr[7]=a7;
    __syncthreads();

    // horizontal: 9 taps x 8 px from fp32 vres (zero pad at w edges)
    const float* vrow = vres + r*WW;
    float o[8];
    #pragma unroll
    for (int j = 0; j < 8; ++j) {
        int wp = px0 + j;
        float a = 0.f;
        #pragma unroll
        for (int t = 0; t < 9; ++t) {
            int wi = wp + t - 4;
            if (wi >= 0 && wi < WW) a += kk.k[t] * vrow[wi];
        }
        o[j] = a;
    }
    uint4 ov;
    ov.x = pack2_bf(o[0],o[1]); ov.y = pack2_bf(o[2],o[3]);
    ov.z = pack2_bf(o[4],o[5]); ov.w = pack2_bf(o[6],o[7]);
    *(uint4*)(mp16 + (size_t)c*HWSZ + (h0 + r)*WW + px0) = ov;
}

// final: ALL c-strided global streams via LDS uint4 (G13).
// mp16 ->(uint4) mpS -> b[] regs; M-mix -> qlds (fp32, unioned with mpS);
// softmax -> smS (same union) ->(uint4) sm16. Clique fixup + smf/redacc sparse.
__launch_bounds__(256)
__global__ void final_kernel(const unsigned short* __restrict__ mp16,
                             unsigned short* __restrict__ sm16,
                             float* __restrict__ smf,
                             float* __restrict__ outHWC,
                             const unsigned short* __restrict__ u16,
                             const int* __restrict__ spT,
                             const int* __restrict__ sp_indices, int iter,
                             const float* __restrict__ Mg,
                             const float* __restrict__ lwg, const float* __restrict__ hwg,
                             K9 kk, float* __restrict__ redacc, int last) {
    __shared__ __align__(16) float qlds[CC*256];          // 21504 B; aliases mpS/smS
    __shared__ __align__(16) unsigned short lu16[CC*256]; // 10752 B
    __shared__ float Bsh[42];
    __shared__ float acc[44];
    __shared__ int anyC;
    unsigned short* mpS = (unsigned short*)qlds;          // [CC*256] bf16 alias

    int bid = blockIdx.x;                      // 0..1023
    int xcd = bid & 7, tt = bid >> 3;
    int h  = xcd*64 + (tt >> 1);
    int w0 = (tt & 1) << 8;
    int tx = threadIdx.x;

    if (tx < 44) acc[tx] = 0.f;
    if (tx == 0) anyC = 0;
    {   // inline B from accumulated partials of this iteration's clique
        const float* rc = redacc + iter*64;
        if (tx < 42) {
            float s = rc[tx], n = rc[42 + tx/21];
            Bsh[tx] = logf((float)HWSZ - n + s);
        }
    }
    // stage u16 half-row (uint4, 672)
    {
        const uint4* src = (const uint4*)(u16 + (size_t)h*ROWF + w0*CC);
        uint4* dst = (uint4*)lu16;
        #pragma unroll
        for (int j = 0; j < 3; ++j) {
            int idx = j*256 + tx;
            if (idx < 672) dst[idx] = src[idx];
        }
    }
    // stage mp16 c-strips (uint4, 672): c = task>>5, q = task&31
    {
        const unsigned short* base = mp16 + (size_t)h*WW + w0;
        #pragma unroll
        for (int j = 0; j < 3; ++j) {
            int task = j*256 + tx;
            if (task < 672) {
                int c = task >> 5, q = task & 31;
                *(uint4*)(mpS + c*256 + q*8) = *(const uint4*)(base + (size_t)c*HWSZ + q*8);
            }
        }
    }
    __syncthreads();

    int w = w0 + tx;
    int p = h*WW + w;

    // blurred field from LDS -> the ONLY register array
    float b[CC];
    #pragma unroll
    for (int c = 0; c < CC; ++c) b[c] = bf16_to_f(mpS[c*256 + tx]);
    __syncthreads();                 // mpS dead -> qlds region writable

    // separable norm = s(h)*s(w)
    float sv = 0.f, swn = 0.f;
    #pragma unroll
    for (int t = 0; t < 9; ++t) {
        int hh = h + t - 4; if (hh >= 0 && hh < HH) sv  += kk.k[t];
        int wi = w + t - 4; if (wi >= 0 && wi < WW) swn += kk.k[t];
    }
    float invnorm = 1.f / (sv * swn);

    int idxv = sp_indices[iter];
    int lab  = spT[p];
    bool in1 = (lab == idxv), in2 = (lab == idxv + 1);
    bool incur = in1 | in2;
    float hw0 = hwg[0], hw1 = hwg[1];
    float attc = hw0 + hw1;

    // M-mix (branch-free); qv -> qlds (own slots only)
    float qmax = -1e30f;
    #pragma unroll
    for (int c = 0; c < CC; ++c) {
        float pw = 0.f;
        #pragma unroll
        for (int k = 0; k < CC; ++k) pw += Mg[c*CC + k] * b[k];
        float qv = bf16_to_f(lu16[tx*CC + c]) - pw*invnorm - attc;
        qlds[c*256 + tx] = qv;
        qmax = fmaxf(qmax, qv);
    }
    // rare clique fixup (~650 px total; own slots)
    if (incur) {
        qmax = -1e30f;
        for (int c = 0; c < CC; ++c) {
            float smv = smf[(size_t)c*HWSZ + p];
            float qm  = (smv == 0.f) ? 1.f : smv;
            float ft1 = in1 ? Bsh[c]      / qm : 0.f;
            float ft2 = in2 ? Bsh[CC + c] / qm : 0.f;
            float fta = ft1 + ft2;
            float att = lwg[c]*ft1 + hw0*(1.f - ft1) + lwg[CC + c]*fta + hw1*(1.f - fta);
            float qv = qlds[c*256 + tx] + attc - att;
            qlds[c*256 + tx] = qv;
            qmax = fmaxf(qmax, qv);
        }
    }

    if (!last) {
        // softmax: exp from own qlds slots into b[]
        float ssum = 0.f;
        #pragma unroll
        for (int c = 0; c < CC; ++c) {
            float e = __expf(qlds[c*256 + tx] - qmax);
            b[c] = e; ssum += e;
        }
        float inv = 1.f / ssum;

        int idx2 = sp_indices[iter + 1];
        bool n1 = (lab == idx2), n2 = (lab == idx2 + 1);
        if (n1 | n2) {
            int mk = n1 ? 0 : 1;
            anyC = 1;
            atomicAdd(&acc[42 + mk], 1.f);
            for (int c = 0; c < CC; ++c) {
                float smv = b[c] * inv;
                smf[(size_t)c*HWSZ + p] = smv;
                atomicAdd(&acc[mk*21 + c], __expf(smv));
            }
        }
        __syncthreads();             // all qv reads done -> smS writable
        #pragma unroll
        for (int c = 0; c < CC; ++c) mpS[c*256 + tx] = f_to_bf16(b[c] * inv);
        if (anyC && tx < 44) atomicAdd(&redacc[(iter+1)*64 + tx], acc[tx]);
        __syncthreads();             // smS complete
        {   // vectorized sm16 stores (uint4, 672)
            unsigned short* dstb = sm16 + (size_t)h*WW + w0;
            #pragma unroll
            for (int j = 0; j < 3; ++j) {
                int task = j*256 + tx;
                if (task < 672) {
                    int c = task >> 5, q = task & 31;
                    *(uint4*)(dstb + (size_t)c*HWSZ + q*8) = *(const uint4*)(mpS + c*256 + q*8);
                }
            }
        }
    } else {
        // q5 -> out HWC: gather float4s directly from qlds, transposed index.
        __syncthreads();
        float4* dst = (float4*)(outHWC + (size_t)h*ROWF + w0*CC);
        #pragma unroll
        for (int j = 0; j < 6; ++j) {
            int idx = j*256 + tx;
            if (idx < CC*256/4) {
                int e = idx * 4;              // e = pix*CC + c
                float4 o;
                o.x = qlds[(e       % CC)*256 + (e       / CC)];
                o.y = qlds[((e + 1) % CC)*256 + ((e + 1) / CC)];
                o.z = qlds[((e + 2) % CC)*256 + ((e + 2) / CC)];
                o.w = qlds[((e + 3) % CC)*256 + ((e + 3) / CC)];
                dst[idx] = o;
            }
        }
    }
}

extern "C" void kernel_launch(void* const* d_in, const int* in_sizes, int n_in,
                              void* d_out, int out_size, void* d_ws, size_t ws_size,
                              hipStream_t stream) {
    const float* unaries    = (const float*)d_in[0];
    // d_in[1] = rgb (unused by the reference)
    const int*   sp_map     = (const int*)d_in[2];
    const int*   sp_indices = (const int*)d_in[3];
    const float* skw        = (const float*)d_in[4];
    const float* bkw        = (const float*)d_in[5];
    const float* cm         = (const float*)d_in[6];
    const float* lw         = (const float*)d_in[7];
    const float* hwt        = (const float*)d_in[8];
    float* out = (float*)d_out;

    char* wsb = (char*)d_ws;
    unsigned short* sm16 = (unsigned short*)wsb;                 // CHW bf16
    unsigned short* mp16 = sm16 + CHW;                           // CHW bf16 (blurred)
    unsigned short* u16  = mp16 + CHW;                           // CHW bf16
    float* smf  = (float*)(u16 + CHW);                           // CHW fp32 (sparse use)
    float* M    = smf + CHW;                                     // 441
    float* redacc = M + CC*CC;                                   // 6 slots x 64
    int*   spT  = (int*)(redacc + 6*64);                         // HWSZ ints

    // 9-tap normalized Gaussian, sigma=3 (fp32, matches reference)
    K9 kk;
    {
        float s = 0.f;
        for (int t = 0; t < 9; ++t) {
            float x = (float)(t - 4) / 3.0f;
            kk.k[t] = expf(-0.5f * x * x);
            s += kk.k[t];
        }
        for (int t = 0; t < 9; ++t) kk.k[t] /= s;
    }

    hipMemsetAsync(redacc, 0, 6*64*sizeof(float), stream);
    convert_u16_kernel<<<CHW/1024, 256, 0, stream>>>(unaries, u16);
    transpose_sp_kernel<<<HWSZ/256, 256, 0, stream>>>(sp_map, spT);
    precomp_M_kernel<<<2, 256, 0, stream>>>(skw, bkw, cm, M);
    init_sm_kernel<<<1024, 256, 0, stream>>>(unaries, sm16, smf, spT, sp_indices, redacc);

    for (int it = 0; it < NITERS; ++it) {
        blur_kernel<<<CC*(HH/BR), 256, 0, stream>>>(sm16, mp16, kk);  // LDS-tiled blur
        int last = (it == NITERS - 1);
        final_kernel<<<1024, 256, 0, stream>>>(mp16, sm16, smf, out, u16, spT,
                                               sp_indices, it, M, lw, hwt,
                                               kk, redacc, last);
    }
}

// Round 16
// 242.082 us; speedup vs baseline: 1.1994x; 1.1268x over previous
//
#include <hip/hip_runtime.h>
#include <cmath>

#define CC 21
#define CP 24                 // padded channels (48 B/px bf16, 16B-aligned)
#define HH 512
#define WW 512
#define HWSZ (HH*WW)
#define CHW (CC*HWSZ)
#define NITERS 5
#define ROWF (CC*WW)          // 10752 fp32 elems per image row in HWC (output)

struct K9 { float k[9]; };

__device__ __forceinline__ float bf16_to_f(unsigned short v) {
    union { unsigned int i; float f; } cv; cv.i = ((unsigned int)v) << 16; return cv.f;
}
__device__ __forceinline__ unsigned short f_to_bf16(float f) {
    union { float f; unsigned int i; } cv; cv.f = f;
    unsigned int b = cv.i + 0x7FFFu + ((cv.i >> 16) & 1u);   // RNE
    return (unsigned short)(b >> 16);
}
__device__ __forceinline__ float lo_bf(unsigned int u) {
    union { unsigned int i; float f; } cv; cv.i = u << 16; return cv.f;
}
__device__ __forceinline__ float hi_bf(unsigned int u) {
    union { unsigned int i; float f; } cv; cv.i = u & 0xFFFF0000u; return cv.f;
}
__device__ __forceinline__ unsigned int pack2_bf(float a, float b) {
    return (unsigned int)f_to_bf16(a) | ((unsigned int)f_to_bf16(b) << 16);
}

// one-time: unaries (HWC 21 fp32) -> uP (px-major 24-ch bf16)
__launch_bounds__(256)
__global__ void convert_uP_kernel(const float* __restrict__ u, unsigned short* __restrict__ uP) {
    int p = blockIdx.x*256 + threadIdx.x;
    const float* s = u + (size_t)p*CC;
    float f[CC];
    #pragma unroll
    for (int c = 0; c < CC; ++c) f[c] = s[c];
    uint4 o0, o1, o2;
    o0.x = pack2_bf(f[0],f[1]);   o0.y = pack2_bf(f[2],f[3]);
    o0.z = pack2_bf(f[4],f[5]);   o0.w = pack2_bf(f[6],f[7]);
    o1.x = pack2_bf(f[8],f[9]);   o1.y = pack2_bf(f[10],f[11]);
    o1.z = pack2_bf(f[12],f[13]); o1.w = pack2_bf(f[14],f[15]);
    o2.x = pack2_bf(f[16],f[17]); o2.y = pack2_bf(f[18],f[19]);
    o2.z = pack2_bf(f[20],0.f);   o2.w = 0u;
    uint4* d = (uint4*)(uP + (size_t)p*CP);
    d[0] = o0; d[1] = o1; d[2] = o2;
}

// spT[h*W + w] = sp_map[w*W + h]
__global__ void transpose_sp_kernel(const int* __restrict__ sp, int* __restrict__ spT) {
    int p = blockIdx.x*256 + threadIdx.x;
    int h = p >> 9, w = p & (WW - 1);
    spT[p] = sp[w*WW + h];
}

// M = CM @ (SKW + BKW)
__global__ void precomp_M_kernel(const float* __restrict__ skw, const float* __restrict__ bkw,
                                 const float* __restrict__ cm, float* __restrict__ M) {
    int i = blockIdx.x * blockDim.x + threadIdx.x;
    if (i >= CC*CC) return;
    int r = i / CC, k = i - r*CC;
    float a = 0.f;
    for (int j = 0; j < CC; ++j) a += cm[r*CC + j] * (skw[j*CC + k] + bkw[j*CC + k]);
    M[i] = a;
}

// iter-0: smP = softmax(uP) + smf/redacc slot-0 at clique-0 px. Pure register path.
__launch_bounds__(256)
__global__ void init_smP_kernel(const unsigned short* __restrict__ uP,
                                unsigned short* __restrict__ smP,
                                float* __restrict__ smf,
                                const int* __restrict__ spT,
                                const int* __restrict__ sp_indices,
                                float* __restrict__ redacc) {
    __shared__ float acc[44];
    __shared__ int anyC;
    int tx = threadIdx.x;
    int p = blockIdx.x*256 + tx;
    if (tx < 44) acc[tx] = 0.f;
    if (tx == 0) anyC = 0;
    __syncthreads();

    const uint4* s = (const uint4*)(uP + (size_t)p*CP);
    uint4 a0 = s[0], a1 = s[1], a2 = s[2];
    unsigned ur[12] = {a0.x,a0.y,a0.z,a0.w, a1.x,a1.y,a1.z,a1.w, a2.x,a2.y,a2.z,a2.w};
    float v[CC]; float m = -1e30f;
    #pragma unroll
    for (int c = 0; c < CC; ++c) {
        v[c] = (c & 1) ? hi_bf(ur[c>>1]) : lo_bf(ur[c>>1]);
        m = fmaxf(m, v[c]);
    }
    float ssum = 0.f;
    #pragma unroll
    for (int c = 0; c < CC; ++c) { v[c] = __expf(v[c] - m); ssum += v[c]; }
    float inv = 1.f / ssum;
    #pragma unroll
    for (int c = 0; c < CC; ++c) v[c] *= inv;

    int idx = sp_indices[0];
    int lab = spT[p];
    if (lab == idx || lab == idx + 1) {
        int mk = (lab == idx) ? 0 : 1;
        anyC = 1;
        atomicAdd(&acc[42 + mk], 1.f);
        for (int c = 0; c < CC; ++c) {
            smf[(size_t)c*HWSZ + p] = v[c];
            atomicAdd(&acc[mk*21 + c], __expf(v[c]));
        }
    }
    uint4 o0, o1, o2;
    o0.x = pack2_bf(v[0],v[1]);   o0.y = pack2_bf(v[2],v[3]);
    o0.z = pack2_bf(v[4],v[5]);   o0.w = pack2_bf(v[6],v[7]);
    o1.x = pack2_bf(v[8],v[9]);   o1.y = pack2_bf(v[10],v[11]);
    o1.z = pack2_bf(v[12],v[13]); o1.w = pack2_bf(v[14],v[15]);
    o2.x = pack2_bf(v[16],v[17]); o2.y = pack2_bf(v[18],v[19]);
    o2.z = pack2_bf(v[20],0.f);   o2.w = 0u;
    uint4* d = (uint4*)(smP + (size_t)p*CP);
    d[0] = o0; d[1] = o1; d[2] = o2;
    __syncthreads();
    if (anyC && tx < 44) atomicAdd(&redacc[tx], acc[tx]);
}

// vertical 9-tap blur (zero pad), px-major: smP -> vtP.
// Thread = one 8-ch slice of one px; 9 aligned uint4 tap loads, coalesced.
// XCD-banded: XCD x handles rows [64x, 64x+64).
__launch_bounds__(256)
__global__ void vblur24_kernel(const unsigned short* __restrict__ smP,
                               unsigned short* __restrict__ vtP, K9 kk) {
    int b = blockIdx.x;                       // 0..3071
    int lb = (b & 7)*384 + (b >> 3);          // XCD band swizzle
    int idx = lb*256 + threadIdx.x;           // 0..786431 slice index
    int px = idx / 3, sub = idx - px*3;
    int h = px >> 9, w = px & (WW - 1);
    float a0=0,a1=0,a2=0,a3=0,a4=0,a5=0,a6=0,a7=0;
    #pragma unroll
    for (int t = 0; t < 9; ++t) {
        int hh = h + t - 4;
        if (hh >= 0 && hh < HH) {
            uint4 v = *(const uint4*)(smP + ((size_t)(hh*WW + w)*CP + sub*8));
            float kt = kk.k[t];
            a0 += kt*lo_bf(v.x); a1 += kt*hi_bf(v.x);
            a2 += kt*lo_bf(v.y); a3 += kt*hi_bf(v.y);
            a4 += kt*lo_bf(v.z); a5 += kt*hi_bf(v.z);
            a6 += kt*lo_bf(v.w); a7 += kt*hi_bf(v.w);
        }
    }
    uint4 o;
    o.x = pack2_bf(a0,a1); o.y = pack2_bf(a2,a3);
    o.z = pack2_bf(a4,a5); o.w = pack2_bf(a6,a7);
    *(uint4*)(vtP + ((size_t)px*CP + sub*8)) = o;
}

// final: hblur (linear-staged LDS halo tile, conflict-free b128 reads) ->
// /norm -> M-mix -> clique fixup -> softmax -> smP (3 uint4, register path)
// + sparse smf/redacc. B inline from redacc slot 'iter'. Last: HWC fp32 out.
__launch_bounds__(256)
__global__ void final24_kernel(const unsigned short* __restrict__ vtP,
                               unsigned short* __restrict__ smP,
                               float* __restrict__ smf,
                               float* __restrict__ outHWC,
                               const unsigned short* __restrict__ uP,
                               const int* __restrict__ spT,
                               const int* __restrict__ sp_indices, int iter,
                               const float* __restrict__ Mg,
                               const float* __restrict__ lwg, const float* __restrict__ hwg,
                               K9 kk, float* __restrict__ redacc, int last) {
    __shared__ __align__(16) char ldsraw[CC*256*4];   // 21504 B union
    __shared__ float Bsh[42];
    __shared__ float acc[44];
    __shared__ int anyC;
    unsigned short* vres = (unsigned short*)ldsraw;   // [264][CP] bf16 = 12672 B
    float* qlds = (float*)ldsraw;                     // [CC][256] fp32 (after barrier)

    int bid = blockIdx.x;                      // 0..1023
    int xcd = bid & 7, tt = bid >> 3;
    int h  = xcd*64 + (tt >> 1);
    int w0 = (tt & 1) << 8;
    int tx = threadIdx.x;

    if (tx < 44) acc[tx] = 0.f;
    if (tx == 0) anyC = 0;
    {   // inline B from accumulated partials of this iteration's clique
        const float* rc = redacc + iter*64;
        if (tx < 42) {
            float s = rc[tx], n = rc[42 + tx/21];
            Bsh[tx] = logf((float)HWSZ - n + s);
        }
    }

    // stage vt half-row + 4px halo each side: 264 px x 3 slices = 792 uint4, linear
    #pragma unroll
    for (int j3 = 0; j3 < 4; ++j3) {
        int s = j3*256 + tx;
        if (s < 792) {
            int j = s / 3, sub = s - j*3;
            int gw = w0 + j - 4;
            uint4 v = make_uint4(0u,0u,0u,0u);
            if (gw >= 0 && gw < WW)
                v = *(const uint4*)(vtP + ((size_t)(h*WW + gw)*CP + sub*8));
            *(uint4*)(vres + j*CP + sub*8) = v;
        }
    }

    int w = w0 + tx;
    int p = h*WW + w;

    // own unaries -> registers (3 aligned uint4)
    const uint4* us = (const uint4*)(uP + (size_t)p*CP);
    uint4 q0 = us[0], q1 = us[1], q2 = us[2];
    unsigned ur[12] = {q0.x,q0.y,q0.z,q0.w, q1.x,q1.y,q1.z,q1.w, q2.x,q2.y,q2.z,q2.w};
    __syncthreads();

    // hblur: 9 taps x 3 b128 reads (48B lane stride = conflict-free)
    float b[CC];
    #pragma unroll
    for (int c = 0; c < CC; ++c) b[c] = 0.f;
    #pragma unroll
    for (int t = 0; t < 9; ++t) {
        const unsigned short* vr = vres + (tx + t)*CP;
        uint4 x0 = *(const uint4*)(vr);
        uint4 x1 = *(const uint4*)(vr + 8);
        uint4 x2 = *(const uint4*)(vr + 16);
        float kt = kk.k[t];
        b[0]  += kt*lo_bf(x0.x); b[1]  += kt*hi_bf(x0.x);
        b[2]  += kt*lo_bf(x0.y); b[3]  += kt*hi_bf(x0.y);
        b[4]  += kt*lo_bf(x0.z); b[5]  += kt*hi_bf(x0.z);
        b[6]  += kt*lo_bf(x0.w); b[7]  += kt*hi_bf(x0.w);
        b[8]  += kt*lo_bf(x1.x); b[9]  += kt*hi_bf(x1.x);
        b[10] += kt*lo_bf(x1.y); b[11] += kt*hi_bf(x1.y);
        b[12] += kt*lo_bf(x1.z); b[13] += kt*hi_bf(x1.z);
        b[14] += kt*lo_bf(x1.w); b[15] += kt*hi_bf(x1.w);
        b[16] += kt*lo_bf(x2.x); b[17] += kt*hi_bf(x2.x);
        b[18] += kt*lo_bf(x2.y); b[19] += kt*hi_bf(x2.y);
        b[20] += kt*lo_bf(x2.z);
    }
    __syncthreads();               // vres dead -> qlds writable

    // separable norm = s(h)*s(w)
    float sv = 0.f, swn = 0.f;
    #pragma unroll
    for (int t = 0; t < 9; ++t) {
        int hh = h + t - 4; if (hh >= 0 && hh < HH) sv  += kk.k[t];
        int wi = w + t - 4; if (wi >= 0 && wi < WW) swn += kk.k[t];
    }
    float invnorm = 1.f / (sv * swn);

    int idxv = sp_indices[iter];
    int lab  = spT[p];
    bool in1 = (lab == idxv), in2 = (lab == idxv + 1);
    bool incur = in1 | in2;
    float hw0 = hwg[0], hw1 = hwg[1];
    float attc = hw0 + hw1;

    // M-mix (branch-free); qv -> qlds
    float qmax = -1e30f;
    #pragma unroll
    for (int c = 0; c < CC; ++c) {
        float pw = 0.f;
        #pragma unroll
        for (int k = 0; k < CC; ++k) pw += Mg[c*CC + k] * b[k];
        float uc = (c & 1) ? hi_bf(ur[c>>1]) : lo_bf(ur[c>>1]);
        float qv = uc - pw*invnorm - attc;
        qlds[c*256 + tx] = qv;
        qmax = fmaxf(qmax, qv);
    }
    // rare clique fixup (~650 px total)
    if (incur) {
        qmax = -1e30f;
        for (int c = 0; c < CC; ++c) {
            float smv = smf[(size_t)c*HWSZ + p];
            float qm  = (smv == 0.f) ? 1.f : smv;
            float ft1 = in1 ? Bsh[c]      / qm : 0.f;
            float ft2 = in2 ? Bsh[CC + c] / qm : 0.f;
            float fta = ft1 + ft2;
            float att = lwg[c]*ft1 + hw0*(1.f - ft1) + lwg[CC + c]*fta + hw1*(1.f - fta);
            float qv = qlds[c*256 + tx] + attc - att;
            qlds[c*256 + tx] = qv;
            qmax = fmaxf(qmax, qv);
        }
    }

    if (!last) {
        // softmax: reuse b[]; store smP straight from registers (3 uint4)
        float ssum = 0.f;
        #pragma unroll
        for (int c = 0; c < CC; ++c) {
            float e = __expf(qlds[c*256 + tx] - qmax);
            b[c] = e; ssum += e;
        }
        float inv = 1.f / ssum;
        uint4 o0, o1, o2;
        o0.x = pack2_bf(b[0]*inv,b[1]*inv);   o0.y = pack2_bf(b[2]*inv,b[3]*inv);
        o0.z = pack2_bf(b[4]*inv,b[5]*inv);   o0.w = pack2_bf(b[6]*inv,b[7]*inv);
        o1.x = pack2_bf(b[8]*inv,b[9]*inv);   o1.y = pack2_bf(b[10]*inv,b[11]*inv);
        o1.z = pack2_bf(b[12]*inv,b[13]*inv); o1.w = pack2_bf(b[14]*inv,b[15]*inv);
        o2.x = pack2_bf(b[16]*inv,b[17]*inv); o2.y = pack2_bf(b[18]*inv,b[19]*inv);
        o2.z = pack2_bf(b[20]*inv,0.f);       o2.w = 0u;
        uint4* d = (uint4*)(smP + (size_t)p*CP);
        d[0] = o0; d[1] = o1; d[2] = o2;

        int idx2 = sp_indices[iter + 1];
        bool n1 = (lab == idx2), n2 = (lab == idx2 + 1);
        if (n1 | n2) {
            int mk = n1 ? 0 : 1;
            anyC = 1;
            atomicAdd(&acc[42 + mk], 1.f);
            for (int c = 0; c < CC; ++c) {
                float smv = b[c] * inv;
                smf[(size_t)c*HWSZ + p] = smv;
                atomicAdd(&acc[mk*21 + c], __expf(smv));
            }
        }
        __syncthreads();
        if (anyC && tx < 44) atomicAdd(&redacc[(iter+1)*64 + tx], acc[tx]);
    } else {
        // q5 -> out (HWC fp32, 21ch): gather float4s from qlds, transposed index.
        __syncthreads();
        float4* dst = (float4*)(outHWC + (size_t)h*ROWF + w0*CC);
        #pragma unroll
        for (int j = 0; j < 6; ++j) {
            int idx = j*256 + tx;
            if (idx < CC*256/4) {
                int e = idx * 4;              // e = pix*CC + c
                float4 o;
                o.x = qlds[(e       % CC)*256 + (e       / CC)];
                o.y = qlds[((e + 1) % CC)*256 + ((e + 1) / CC)];
                o.z = qlds[((e + 2) % CC)*256 + ((e + 2) / CC)];
                o.w = qlds[((e + 3) % CC)*256 + ((e + 3) / CC)];
                dst[idx] = o;
            }
        }
    }
}

extern "C" void kernel_launch(void* const* d_in, const int* in_sizes, int n_in,
                              void* d_out, int out_size, void* d_ws, size_t ws_size,
                              hipStream_t stream) {
    const float* unaries    = (const float*)d_in[0];
    // d_in[1] = rgb (unused by the reference)
    const int*   sp_map     = (const int*)d_in[2];
    const int*   sp_indices = (const int*)d_in[3];
    const float* skw        = (const float*)d_in[4];
    const float* bkw        = (const float*)d_in[5];
    const float* cm         = (const float*)d_in[6];
    const float* lw         = (const float*)d_in[7];
    const float* hwt        = (const float*)d_in[8];
    float* out = (float*)d_out;

    char* wsb = (char*)d_ws;
    unsigned short* smP = (unsigned short*)wsb;                  // HW*24 bf16 (12.6MB)
    unsigned short* vtP = smP + (size_t)HWSZ*CP;                 // HW*24 bf16
    unsigned short* uP  = vtP + (size_t)HWSZ*CP;                 // HW*24 bf16
    float* smf  = (float*)(uP + (size_t)HWSZ*CP);                // CHW fp32 (sparse use)
    float* M    = smf + CHW;                                     // 441
    float* redacc = M + CC*CC;                                   // 6 slots x 64
    int*   spT  = (int*)(redacc + 6*64);                         // HWSZ ints

    // 9-tap normalized Gaussian, sigma=3 (fp32, matches reference)
    K9 kk;
    {
        float s = 0.f;
        for (int t = 0; t < 9; ++t) {
            float x = (float)(t - 4) / 3.0f;
            kk.k[t] = expf(-0.5f * x * x);
            s += kk.k[t];
        }
        for (int t = 0; t < 9; ++t) kk.k[t] /= s;
    }

    hipMemsetAsync(redacc, 0, 6*64*sizeof(float), stream);
    convert_uP_kernel<<<HWSZ/256, 256, 0, stream>>>(unaries, uP);
    transpose_sp_kernel<<<HWSZ/256, 256, 0, stream>>>(sp_map, spT);
    precomp_M_kernel<<<2, 256, 0, stream>>>(skw, bkw, cm, M);
    init_smP_kernel<<<HWSZ/256, 256, 0, stream>>>(uP, smP, smf, spT, sp_indices, redacc);

    for (int it = 0; it < NITERS; ++it) {
        vblur24_kernel<<<3*HWSZ/256, 256, 0, stream>>>(smP, vtP, kk);
        int last = (it == NITERS - 1);
        final24_kernel<<<1024, 256, 0, stream>>>(vtP, smP, smf, out, uP, spT,
                                                 sp_indices, it, M, lw, hwt,
                                                 kk, redacc, last);
    }
}